// Round 12
// baseline (222.655 us; speedup 1.0000x reference)
//
#include <hip/hip_runtime.h>
#include <float.h>

// VQ-VAE nearest-codeword + loss, bf16x2-emulated fp32 GEMM on MFMA.
// feature: [8192, 512] fp32 -> rows f: [32768, 128]
// W: [2048, 128] fp32
// d_out: loss[8192] fp32, then out[32768*128] fp32
// R12: spill-free streaming design. B-fragments stream global(L2)->reg->MFMA,
// no LDS W buffer, no staging registers, no main-loop barriers, rf=1.
// Diagnosis from R11 counters: WRITE_SIZE 39.8MB vs 17MB output = scratch spills.

#define NROWS 32768
#define DIM   128
#define NCODE 2048
#define BM    64             // rows per block -> grid 512 = 2 blocks/CU
#define NT    (NCODE / 16)   // 128 code tiles
#define TAU   0.02f          // rescore threshold (bf16x2 3-pass error ~2e-3)

typedef __attribute__((ext_vector_type(8))) short short8v;  // 8 bf16 (4 VGPR)
typedef __attribute__((ext_vector_type(4))) float f32x4;

static __device__ __forceinline__ unsigned short f2bf_rne(float x) {
    unsigned u = __float_as_uint(x);
    unsigned r = u + 0x7FFFu + ((u >> 16) & 1u);
    return (unsigned short)(r >> 16);
}
static __device__ __forceinline__ float bf2f(unsigned short h) {
    return __uint_as_float(((unsigned)h) << 16);
}

// ---------------- prep: W fp32 -> frag-major bf16 hi/lo + wsq ----------------
// whi[tile][kc][gg][c][8] (strides in shorts: tile 2048, kc 512, gg 128, c 8)
// value = bf16(W[tile*16+c][kc*32+gg*8+e]).  One thread per (code, 8-dim group).
__global__ __launch_bounds__(256)
void vq_prep(const float* __restrict__ W, short* __restrict__ whi,
             short* __restrict__ wlo, float* __restrict__ wsq) {
    const int t    = blockIdx.x * 256 + threadIdx.x;  // 0..32767
    const int code = t >> 4;
    const int g    = t & 15;
    const float* src = W + (size_t)code * DIM + g * 8;

    float4 u0 = *(const float4*)(src);
    float4 u1 = *(const float4*)(src + 4);
    float xs[8] = { u0.x, u0.y, u0.z, u0.w, u1.x, u1.y, u1.z, u1.w };

    short8v hi, lo;
    float p = 0.0f;
    #pragma unroll
    for (int e = 0; e < 8; ++e) {
        unsigned short hb = f2bf_rne(xs[e]);
        float rem = xs[e] - bf2f(hb);
        unsigned short lb = f2bf_rne(rem);
        hi[e] = (short)hb; lo[e] = (short)lb;
        p = fmaf(xs[e], xs[e], p);
    }
    p += __shfl_xor(p, 1, 64);
    p += __shfl_xor(p, 2, 64);
    p += __shfl_xor(p, 4, 64);
    p += __shfl_xor(p, 8, 64);
    if (g == 0) wsq[code] = p;

    const int tile = code >> 4;
    const int c    = code & 15;
    const int kc   = g >> 2;
    const int gg   = g & 3;
    const size_t off = (size_t)tile * 2048 + (size_t)kc * 512 + (size_t)gg * 128 + (size_t)c * 8;
    *(short8v*)(whi + off) = hi;
    *(short8v*)(wlo + off) = lo;
}

// ---------------- main MFMA kernel ----------------
// 256 threads = 4 waves, each wave owns 16 rows (rf=1) x all 2048 codes.
// No cross-wave merge; no barriers in the main loop.
__global__ __launch_bounds__(256, 2)
void vq_mfma(const float* __restrict__ feature, const float* __restrict__ W,
             const short* __restrict__ whi, const short* __restrict__ wlo,
             const float* __restrict__ wsqg, float* __restrict__ out) {
    __shared__ float wsq_l[NCODE];     // 8 KB
    __shared__ float dist_l[BM];
    __shared__ int   j_l[BM];
    __shared__ float fsq_l[BM];
    __shared__ int   flags[BM + 4];
    __shared__ float frow[DIM];
    __shared__ float rbest[4];
    __shared__ int   rbj[4];

    const int tid  = threadIdx.x;
    const int lane = tid & 63;
    const int w    = tid >> 6;     // wave 0..3 -> rows w*16..w*16+15
    const int c    = lane & 15;
    const int g    = lane >> 4;
    const int rb   = blockIdx.x;   // 512 blocks of 64 rows

    if (tid == 0) flags[0] = 0;

    // stage wsq to LDS (2048 floats / 256 threads = 8 each)
    {
        float4 a = *(const float4*)(wsqg + tid * 8);
        float4 b = *(const float4*)(wsqg + tid * 8 + 4);
        *(float4*)&wsq_l[tid * 8]     = a;
        *(float4*)&wsq_l[tid * 8 + 4] = b;
    }

    // ---- A-fragments (rf=1): lane holds f[row=c][k=kc*32+g*8+e], bf16 hi/lo ----
    short8v Ahi[4], Alo[4];
    {
        const int row = rb * BM + w * 16 + c;
        const float* fp = feature + (size_t)row * DIM + g * 8;
        float fs = 0.0f;
        #pragma unroll
        for (int kc = 0; kc < 4; ++kc) {
            float4 u0 = *(const float4*)(fp + kc * 32);
            float4 u1 = *(const float4*)(fp + kc * 32 + 4);
            float xs[8] = { u0.x, u0.y, u0.z, u0.w, u1.x, u1.y, u1.z, u1.w };
            short8v hi, lo;
            #pragma unroll
            for (int e = 0; e < 8; ++e) {
                unsigned short hb = f2bf_rne(xs[e]);
                float rem = xs[e] - bf2f(hb);
                unsigned short lb = f2bf_rne(rem);
                hi[e] = (short)hb; lo[e] = (short)lb;
                fs = fmaf(xs[e], xs[e], fs);
            }
            Ahi[kc] = hi; Alo[kc] = lo;
        }
        fs += __shfl_xor(fs, 16, 64);
        fs += __shfl_xor(fs, 32, 64);
        if (g == 0) fsq_l[w * 16 + c] = fs;
    }

    float s1[4], s2[4];
    int   j1[4];
    #pragma unroll
    for (int q = 0; q < 4; ++q) { s1[q] = FLT_MAX; s2[q] = FLT_MAX; j1[q] = NCODE; }

    __syncthreads();  // wsq_l ready

    // ---- main loop: stream B from global (L2-resident), 2-deep prefetch ----
    const short* bhp = whi + (size_t)lane * 8;
    const short* blp = wlo + (size_t)lane * 8;

    short8v BhA[4], BlA[4], BhB[4], BlB[4];
    #pragma unroll
    for (int kc = 0; kc < 4; ++kc) {
        BhA[kc] = *(const short8v*)(bhp + kc * 512);
        BlA[kc] = *(const short8v*)(blp + kc * 512);
    }

    #define VQ_COMPUTE(T, Bh, Bl) do {                                             \
        const int   codebase = (T) * 16 + c;                                       \
        const float wq       = wsq_l[codebase];                                    \
        f32x4 ahh = {0.f, 0.f, 0.f, 0.f};                                          \
        f32x4 ahl = {0.f, 0.f, 0.f, 0.f};                                          \
        f32x4 alh = {0.f, 0.f, 0.f, 0.f};                                          \
        _Pragma("unroll")                                                          \
        for (int kc = 0; kc < 4; ++kc) {                                           \
            ahh = __builtin_amdgcn_mfma_f32_16x16x32_bf16(Ahi[kc], Bh[kc], ahh, 0, 0, 0); \
            ahl = __builtin_amdgcn_mfma_f32_16x16x32_bf16(Ahi[kc], Bl[kc], ahl, 0, 0, 0); \
            alh = __builtin_amdgcn_mfma_f32_16x16x32_bf16(Alo[kc], Bh[kc], alh, 0, 0, 0); \
        }                                                                          \
        _Pragma("unroll")                                                          \
        for (int q = 0; q < 4; ++q) {                                              \
            float dot = ahh[q] + ahl[q] + alh[q];                                  \
            float s   = fmaf(-2.0f, dot, wq);                                      \
            bool  lt  = s < s1[q];                                                 \
            s2[q] = fminf(s2[q], lt ? s1[q] : s);                                  \
            j1[q] = lt ? codebase : j1[q];                                         \
            s1[q] = lt ? s : s1[q];                                                \
        }                                                                          \
    } while (0)

    for (int T = 0; T < NT; T += 2) {
        {   // prefetch T+1 into set B (T+1 = 127 max, always valid)
            const short* ph = bhp + (size_t)(T + 1) * 2048;
            const short* pl = blp + (size_t)(T + 1) * 2048;
            #pragma unroll
            for (int kc = 0; kc < 4; ++kc) {
                BhB[kc] = *(const short8v*)(ph + kc * 512);
                BlB[kc] = *(const short8v*)(pl + kc * 512);
            }
        }
        VQ_COMPUTE(T, BhA, BlA);
        if (T + 2 < NT) {   // prefetch T+2 into set A
            const short* ph = bhp + (size_t)(T + 2) * 2048;
            const short* pl = blp + (size_t)(T + 2) * 2048;
            #pragma unroll
            for (int kc = 0; kc < 4; ++kc) {
                BhA[kc] = *(const short8v*)(ph + kc * 512);
                BlA[kc] = *(const short8v*)(pl + kc * 512);
            }
        }
        VQ_COMPUTE(T + 1, BhB, BlB);
    }
    #undef VQ_COMPUTE

    // ---- cross-lane top-2 merge over the 16 code-lanes ----
    #pragma unroll
    for (int q = 0; q < 4; ++q) {
        float a1 = s1[q]; int aj = j1[q]; float a2 = s2[q];
        #pragma unroll
        for (int m = 1; m < 16; m <<= 1) {
            float b1 = __shfl_xor(a1, m, 64);
            int   bj = __shfl_xor(aj, m, 64);
            float b2 = __shfl_xor(a2, m, 64);
            bool swap = (b1 < a1) || (b1 == a1 && bj < aj);
            float other1 = swap ? a1 : b1;
            a2 = fminf(fminf(a2, b2), other1);
            a1 = swap ? b1 : a1;
            aj = swap ? bj : aj;
        }
        if (c == 0) {
            const int row = w * 16 + g * 4 + q;
            dist_l[row] = a1;
            j_l[row]    = aj;
            if (a2 - a1 < TAU) {
                int idx = atomicAdd(&flags[0], 1);
                flags[1 + idx] = row;
            }
        }
    }
    __syncthreads();

    // ---- exact fp32 rescore for flagged rows (rare) ----
    const int nf = flags[0];
    for (int i = 0; i < nf; ++i) {
        const int row = flags[1 + i];
        if (tid < 32) {
            float4 v = *(const float4*)(feature + ((size_t)(rb * BM + row)) * DIM + tid * 4);
            *(float4*)&frow[tid * 4] = v;
        }
        __syncthreads();
        float best = FLT_MAX; int bj = NCODE;
        #pragma unroll 1
        for (int cc = 0; cc < 8; ++cc) {
            const int code = tid * 8 + cc;
            const float* wp = W + (size_t)code * DIM;
            float d = 0.0f;
            #pragma unroll
            for (int k = 0; k < DIM; k += 4) {
                float4 wv = *(const float4*)(wp + k);
                d = fmaf(wv.x, frow[k],     d);
                d = fmaf(wv.y, frow[k + 1], d);
                d = fmaf(wv.z, frow[k + 2], d);
                d = fmaf(wv.w, frow[k + 3], d);
            }
            float s = wsq_l[code] - 2.0f * d;
            if (s < best) { best = s; bj = code; }
        }
        #pragma unroll
        for (int m = 1; m < 64; m <<= 1) {
            float ob = __shfl_xor(best, m, 64);
            int   oj = __shfl_xor(bj, m, 64);
            if (ob < best || (ob == best && oj < bj)) { best = ob; bj = oj; }
        }
        if (lane == 0) { rbest[w] = best; rbj[w] = bj; }
        __syncthreads();
        if (tid == 0) {
            float bb = rbest[0]; int jj = rbj[0];
            #pragma unroll
            for (int ww = 1; ww < 4; ++ww) {
                if (rbest[ww] < bb || (rbest[ww] == bb && rbj[ww] < jj)) { bb = rbest[ww]; jj = rbj[ww]; }
            }
            dist_l[row] = bb; j_l[row] = jj;
        }
        __syncthreads();
    }

    // ---- loss: 16 batch rows per block ----
    if (tid < 16) {
        float s = 0.0f;
        #pragma unroll
        for (int sl = 0; sl < 4; ++sl) {
            int r = tid * 4 + sl;
            s += dist_l[r] + fsq_l[r];
        }
        out[(size_t)rb * 16 + tid] = 0.3125f * s;  // 1.25 / 4
    }

    // ---- gather out rows: 4 threads per row ----
    {
        const int row = tid >> 2;     // 0..63
        const int q   = tid & 3;
        const int j   = j_l[row];
        const float4* src = (const float4*)(W + (size_t)j * DIM + q * 32);
        float4* dst = (float4*)(out + 8192 + ((size_t)(rb * BM + row)) * DIM + q * 32);
        #pragma unroll
        for (int k8 = 0; k8 < 8; ++k8) dst[k8] = src[k8];
    }
}

// ---------------- fallback (round-1 fp32 VALU path, used if ws too small) ----------------
#define F_BM  64
#define F_BN  128
#define F_BK  32
#define F_LDF 132
#define F_LDW 36

__global__ __launch_bounds__(256)
void wsq_kernel(const float* __restrict__ W, float* __restrict__ wsq) {
    const int wv   = threadIdx.x >> 6;
    const int lane = threadIdx.x & 63;
    const int code = blockIdx.x * 4 + wv;
    float2 v = *(const float2*)(W + (size_t)code * DIM + lane * 2);
    float p = v.x * v.x + v.y * v.y;
    #pragma unroll
    for (int m = 1; m < 64; m <<= 1) p += __shfl_xor(p, m, 64);
    if (lane == 0) wsq[code] = p;
}

__global__ __launch_bounds__(256, 3)
void vq_main(const float* __restrict__ feature, const float* __restrict__ W,
             const float* __restrict__ wsq, float* __restrict__ out) {
    __shared__ float lds_f[F_BM * F_LDF];
    __shared__ float lds_w[F_BN * F_LDW];
    __shared__ float dl[F_BM];
    __shared__ int   jl[F_BM];

    const int tid = threadIdx.x;
    const int tx  = tid & 15;
    const int ty  = tid >> 4;
    const int rbk = blockIdx.x;

    {
        const float* fbase = feature + (size_t)rbk * F_BM * DIM;
        #pragma unroll
        for (int t = 0; t < 8; ++t) {
            int f4 = tid + t * 256;
            int row = f4 >> 5, dcol = (f4 & 31) << 2;
            float4 v = *(const float4*)(fbase + (size_t)f4 * 4);
            *(float4*)&lds_f[row * F_LDF + dcol] = v;
        }
    }

    float run_s[4]; int run_j[4];
    #pragma unroll
    for (int rr = 0; rr < 4; ++rr) { run_s[rr] = 3.4e38f; run_j[rr] = 0; }

    for (int cb = 0; cb < NCODE / F_BN; ++cb) {
        float acc[4][8];
        #pragma unroll
        for (int rr = 0; rr < 4; ++rr)
            #pragma unroll
            for (int cc = 0; cc < 8; ++cc) acc[rr][cc] = 0.0f;

        for (int dc = 0; dc < DIM / F_BK; ++dc) {
            __syncthreads();
            #pragma unroll
            for (int t = 0; t < 4; ++t) {
                int f4 = tid + t * 256;
                int cx = f4 >> 3, dd4 = (f4 & 7) << 2;
                float4 v = *(const float4*)(W + ((size_t)(cb * F_BN + cx)) * DIM + dc * F_BK + dd4);
                *(float4*)&lds_w[cx * F_LDW + dd4] = v;
            }
            __syncthreads();

            #pragma unroll
            for (int dd = 0; dd < F_BK; dd += 4) {
                float4 fa[4];
                #pragma unroll
                for (int rr = 0; rr < 4; ++rr)
                    fa[rr] = *(const float4*)&lds_f[(ty * 4 + rr) * F_LDF + dc * F_BK + dd];
                float4 wb[8];
                #pragma unroll
                for (int cc = 0; cc < 8; ++cc)
                    wb[cc] = *(const float4*)&lds_w[(cc * 16 + tx) * F_LDW + dd];
                #pragma unroll
                for (int rr = 0; rr < 4; ++rr)
                    #pragma unroll
                    for (int cc = 0; cc < 8; ++cc) {
                        float a = acc[rr][cc];
                        a = fmaf(fa[rr].x, wb[cc].x, a);
                        a = fmaf(fa[rr].y, wb[cc].y, a);
                        a = fmaf(fa[rr].z, wb[cc].z, a);
                        a = fmaf(fa[rr].w, wb[cc].w, a);
                        acc[rr][cc] = a;
                    }
            }
        }

        float ws8[8];
        #pragma unroll
        for (int cc = 0; cc < 8; ++cc) ws8[cc] = wsq[cb * F_BN + cc * 16 + tx];

        #pragma unroll
        for (int rr = 0; rr < 4; ++rr) {
            float bs = 3.4e38f; int bj = 0x7fffffff;
            #pragma unroll
            for (int cc = 0; cc < 8; ++cc) {
                int code = cb * F_BN + cc * 16 + tx;
                float s = ws8[cc] - 2.0f * acc[rr][cc];
                if (s < bs) { bs = s; bj = code; }
            }
            #pragma unroll
            for (int m = 1; m < 16; m <<= 1) {
                float os = __shfl_xor(bs, m, 64);
                int   oj = __shfl_xor(bj, m, 64);
                if (os < bs || (os == bs && oj < bj)) { bs = os; bj = oj; }
            }
            if (bs < run_s[rr] || (bs == run_s[rr] && bj < run_j[rr])) { run_s[rr] = bs; run_j[rr] = bj; }
        }
    }

    if (tx == 0)
        #pragma unroll
        for (int rr = 0; rr < 4; ++rr) { dl[ty * 4 + rr] = run_s[rr]; jl[ty * 4 + rr] = run_j[rr]; }
    __syncthreads();

    const int row = tid >> 2;
    const int q   = tid & 3;
    {
        float p = 0.0f;
        const float* fr = &lds_f[row * F_LDF + q * 32];
        #pragma unroll
        for (int k8 = 0; k8 < 8; ++k8) {
            float4 v = *(const float4*)&fr[k8 * 4];
            p = fmaf(v.x, v.x, p); p = fmaf(v.y, v.y, p);
            p = fmaf(v.z, v.z, p); p = fmaf(v.w, v.w, p);
        }
        p += __shfl_xor(p, 1, 64);
        p += __shfl_xor(p, 2, 64);
        if (q == 0) dl[row] += p;
    }
    __syncthreads();

    if (tid < 16) {
        float s = dl[tid * 4] + dl[tid * 4 + 1] + dl[tid * 4 + 2] + dl[tid * 4 + 3];
        out[(size_t)rbk * 16 + tid] = 0.3125f * s;
    }
    {
        int j = jl[row];
        const float4* src = (const float4*)(W + (size_t)j * DIM + q * 32);
        float4* dst = (float4*)(out + 8192 + ((size_t)(rbk * F_BM + row)) * DIM + q * 32);
        #pragma unroll
        for (int k8 = 0; k8 < 8; ++k8) dst[k8] = src[k8];
    }
}

extern "C" void kernel_launch(void* const* d_in, const int* in_sizes, int n_in,
                              void* d_out, int out_size, void* d_ws, size_t ws_size,
                              hipStream_t stream) {
    const float* feature = (const float*)d_in[0];
    const float* W       = (const float*)d_in[1];
    float*       out     = (float*)d_out;

    const size_t need = 2u * 524288u + 8192u;  // whi + wlo + wsq
    if (ws_size >= need) {
        short* whi = (short*)d_ws;
        short* wlo = whi + 262144;
        float* wsq = (float*)((char*)d_ws + 1048576);
        vq_prep<<<128, 256, 0, stream>>>(W, whi, wlo, wsq);
        vq_mfma<<<512, 256, 0, stream>>>(feature, W, whi, wlo, wsq, out);
    } else {
        float* wsq = (float*)d_ws;
        wsq_kernel<<<512, 256, 0, stream>>>(W, wsq);
        vq_main<<<512, 256, 0, stream>>>(feature, W, wsq, out);
    }
}